// Round 4
// baseline (1314.387 us; speedup 1.0000x reference)
//
#include <hip/hip_runtime.h>
#include <stdint.h>
#include <math.h>

#define NALPH 128
#define NEMB  128
#define NST   512
#define BATCH 256
#define TLEN  256
#define FANIN 640   // NEMB + NST

#if __has_builtin(__builtin_amdgcn_sdot4)
#define SDOT4(a, b, c) __builtin_amdgcn_sdot4((a), (b), (c), false)
#else
__device__ __forceinline__ int SDOT4(int a, int b, int c) {
  c += (int)(signed char)(a)       * (int)(signed char)(b);
  c += (int)(signed char)(a >> 8)  * (int)(signed char)(b >> 8);
  c += (int)(signed char)(a >> 16) * (int)(signed char)(b >> 16);
  c += (int)(signed char)(a >> 24) * (int)(signed char)(b >> 24);
  return c;
}
#endif

// swap adjacent lanes (2k <-> 2k+1): DPP quad_perm(1,0,3,2) = 0xB1
__device__ __forceinline__ int dpp_xor1(int v) {
  return __builtin_amdgcn_update_dpp(0, v, 0xB1, 0xF, 0xF, true);
}

// ---------------------------------------------------------------------------
// k_prep (896 blocks x 256 thr):
//  [0,256)    G[tok*512+n] = b_in[n] + sum_e emb[tok,e]*W_in[n,e]  (fp32 exact)
//  [256,768)  W_s row n quant -> WqI[j*1024 + t] (t = n*2+h, j in [0,64)),
//             Sd[n] = rowmax/16129
//  [768,896)  W_out row a quant -> WoI[i*1024 + t] (t = (q*128+a)*2+h, i in
//             [0,16), dword covers K byte 256h+64q+4i), So[a] = rowmax/16129
// ---------------------------------------------------------------------------
__global__ __launch_bounds__(256) void k_prep(
    const float* __restrict__ emb, const float* __restrict__ W_in,
    const float* __restrict__ b_in, const float* __restrict__ W_out,
    float* __restrict__ G, int* __restrict__ WqI, float* __restrict__ Sd,
    int* __restrict__ WoI, float* __restrict__ So)
{
  int bid = blockIdx.x, tid = threadIdx.x;
  if (bid < 256) {
    int idx = bid * 256 + tid;           // tok*512 + n
    int tok = idx >> 9, n = idx & 511;
    const float4* er4 = (const float4*)(emb + tok * NEMB);
    const float4* wr4 = (const float4*)(W_in + (size_t)n * FANIN);
    float acc = b_in[n];
#pragma unroll 8
    for (int e = 0; e < NEMB / 4; ++e) {
      float4 av = er4[e], bv = wr4[e];
      acc += av.x * bv.x + av.y * bv.y + av.z * bv.z + av.w * bv.w;
    }
    G[idx] = acc;
  } else if (bid < 768) {
    int n = bid - 256;                   // W_s row
    __shared__ float smax[128];
    float lw[4]; float m = 0.f;
    if (tid < 128) {
      const float* wr = W_in + (size_t)n * FANIN + NEMB + tid * 4;
#pragma unroll
      for (int i = 0; i < 4; ++i) { lw[i] = wr[i]; m = fmaxf(m, fabsf(lw[i])); }
      smax[tid] = m;
    }
    __syncthreads();
    for (int s2 = 64; s2 > 0; s2 >>= 1) {
      if (tid < s2) smax[tid] = fmaxf(smax[tid], smax[tid + s2]);
      __syncthreads();
    }
    float mx = smax[0];
    if (tid < 128) {
      float r = 127.f / mx;
      uint32_t pk = 0;
#pragma unroll
      for (int i = 0; i < 4; ++i) {
        int qv = (int)rintf(lw[i] * r);
        qv = qv < -127 ? -127 : (qv > 127 ? 127 : qv);
        pk |= (uint32_t)(qv & 0xff) << (8 * i);
      }
      int h = tid >> 6, j = tid & 63;
      WqI[j * 1024 + (n << 1) + h] = (int)pk;
    }
    if (tid == 0) Sd[n] = mx / 16129.0f;
  } else {
    int a = bid - 768;                   // W_out row
    __shared__ float smax[128];
    float lw[4]; float m = 0.f;
    if (tid < 128) {
      const float* wr = W_out + (size_t)a * NST + tid * 4;
#pragma unroll
      for (int i = 0; i < 4; ++i) { lw[i] = wr[i]; m = fmaxf(m, fabsf(lw[i])); }
      smax[tid] = m;
    }
    __syncthreads();
    for (int s2 = 64; s2 > 0; s2 >>= 1) {
      if (tid < s2) smax[tid] = fmaxf(smax[tid], smax[tid + s2]);
      __syncthreads();
    }
    float mx = smax[0];
    if (tid < 128) {
      float r = 127.f / mx;
      uint32_t pk = 0;
#pragma unroll
      for (int i = 0; i < 4; ++i) {
        int qv = (int)rintf(lw[i] * r);
        qv = qv < -127 ? -127 : (qv > 127 ? 127 : qv);
        pk |= (uint32_t)(qv & 0xff) << (8 * i);
      }
      int h = tid >> 6, rem = tid & 63, q = rem >> 4, i = rem & 15;
      WoI[i * 1024 + ((q * 128 + a) << 1) + h] = (int)pk;
    }
    if (tid == 0) So[a] = mx / 16129.0f;
  }
}

// ---------------------------------------------------------------------------
// k_rec: 256 blocks x 1024 threads. Lane-pair K-split: thread t -> column
// n = t>>1, K-half h = t&1 (adjacent lanes). wq[64]+woq[16] i8 dwords in
// VGPRs. Per step: 16 broadcast ds_read_b128 -> 64 recur dot4 + 16 y dot4;
// cross-half reduce via DPP quad_perm swap (in-register); ONE barrier/step.
// y partials double-buffered in LDS, reduced by threads t<128 post-barrier.
// ---------------------------------------------------------------------------
__global__ __attribute__((amdgpu_flat_work_group_size(1024, 1024),
                          amdgpu_waves_per_eu(4, 4))) void k_rec(
    const int* __restrict__ w, const float* __restrict__ G,
    const int* __restrict__ WqI, const float* __restrict__ Sd,
    const int* __restrict__ WoI, const float* __restrict__ So,
    const float* __restrict__ b_out, float* __restrict__ y)
{
  __shared__ __align__(16) signed char qs[2][NST];   // i8 state, double-buffered
  __shared__ int py[2][NST];                          // y partials, double-buffered

  int t = threadIdx.x;
  int row = blockIdx.x;
  int n = t >> 1;                        // column owned (shared by lane pair)
  int h = t & 1;                         // K-half
  int h256 = h << 8;
  int qq = __builtin_amdgcn_readfirstlane(t >> 8);   // y K-quarter, wave-uniform

  int wq[64];
#pragma unroll
  for (int j = 0; j < 64; ++j) wq[j] = WqI[j * 1024 + t];   // coalesced
  int woq[16];
#pragma unroll
  for (int i = 0; i < 16; ++i) woq[i] = WoI[i * 1024 + t];  // coalesced

  float dn = Sd[n];
  float so_r = So[t & 127];
  float bo_r = b_out[t & 127];

  if (t < 128) ((int*)&qs[0][0])[t] = 0;
  __syncthreads();

  const int* wr = w + row * TLEN;
  float* yrow = y + (size_t)row * TLEN * 128;

  float g = G[wr[0] * NST + n];

  for (int tt = 0; tt < TLEN; ++tt) {
    int p = tt & 1;
    // ---- dots on qs[p] = s_{tt-1} (this thread's K-half) ----
    const int4* sp = (const int4*)(&qs[0][0] + (p << 9) + h256);
    int a0 = 0, a1 = 0, a2 = 0, a3 = 0, ay = 0;
#pragma unroll
    for (int rq = 0; rq < 4; ++rq) {
      int4 s0 = sp[rq * 4 + 0];
      int4 s1 = sp[rq * 4 + 1];
      int4 s2 = sp[rq * 4 + 2];
      int4 s3 = sp[rq * 4 + 3];
      a0 = SDOT4(wq[16 * rq + 0], s0.x, a0);
      a1 = SDOT4(wq[16 * rq + 1], s0.y, a1);
      a2 = SDOT4(wq[16 * rq + 2], s0.z, a2);
      a3 = SDOT4(wq[16 * rq + 3], s0.w, a3);
      a0 = SDOT4(wq[16 * rq + 4], s1.x, a0);
      a1 = SDOT4(wq[16 * rq + 5], s1.y, a1);
      a2 = SDOT4(wq[16 * rq + 6], s1.z, a2);
      a3 = SDOT4(wq[16 * rq + 7], s1.w, a3);
      a0 = SDOT4(wq[16 * rq + 8], s2.x, a0);
      a1 = SDOT4(wq[16 * rq + 9], s2.y, a1);
      a2 = SDOT4(wq[16 * rq + 10], s2.z, a2);
      a3 = SDOT4(wq[16 * rq + 11], s2.w, a3);
      a0 = SDOT4(wq[16 * rq + 12], s3.x, a0);
      a1 = SDOT4(wq[16 * rq + 13], s3.y, a1);
      a2 = SDOT4(wq[16 * rq + 14], s3.z, a2);
      a3 = SDOT4(wq[16 * rq + 15], s3.w, a3);
      if (rq == qq) {                    // wave-uniform branch
        ay = SDOT4(woq[0], s0.x, ay);  ay = SDOT4(woq[1], s0.y, ay);
        ay = SDOT4(woq[2], s0.z, ay);  ay = SDOT4(woq[3], s0.w, ay);
        ay = SDOT4(woq[4], s1.x, ay);  ay = SDOT4(woq[5], s1.y, ay);
        ay = SDOT4(woq[6], s1.z, ay);  ay = SDOT4(woq[7], s1.w, ay);
        ay = SDOT4(woq[8], s2.x, ay);  ay = SDOT4(woq[9], s2.y, ay);
        ay = SDOT4(woq[10], s2.z, ay); ay = SDOT4(woq[11], s2.w, ay);
        ay = SDOT4(woq[12], s3.x, ay); ay = SDOT4(woq[13], s3.y, ay);
        ay = SDOT4(woq[14], s3.z, ay); ay = SDOT4(woq[15], s3.w, ay);
      }
    }
    // ---- in-register cross-half reduce (lane pair) ----
    int ar = (a0 + a1) + (a2 + a3);
    ar += dpp_xor1(ar);                  // both lanes: full 512-dot
    ay += dpp_xor1(ay);                  // both lanes: K-quarter-pair partial

    // ---- activation (both lanes redundantly; no divergence) ----
    float av = fmaf((float)ar, dn, g);
    av = fminf(fmaxf(av, -15.f), 15.f);
    float e = __expf(2.f * av);
    float s = (e - 1.f) * __builtin_amdgcn_rcpf(e + 1.f);
    int q8 = (int)rintf(s * 127.f);

    if (h == 0) {
      qs[p ^ 1][n] = (signed char)q8;
      py[p][n] = ay;
    }
    __syncthreads();                     // the ONE barrier per step

    // ---- y_{tt-1} final reduce (2 waves), overlapped with next step's dots
    if (tt && t < 128) {
      int sum = py[p][t] + py[p][t + 128] + py[p][t + 256] + py[p][t + 384];
      yrow[(size_t)(tt - 1) * 128 + t] = fmaf((float)sum, so_r, bo_r);
    }
    // ---- prefetch next fin ----
    int tok_n = wr[(tt + 1) & (TLEN - 1)];
    g = G[tok_n * NST + n];
  }

  // ---- epilogue: y_255 from s_255 (in qs[0]) ----
  {
    const int4* sp = (const int4*)(&qs[0][0] + h256);
    int ay = 0;
#pragma unroll
    for (int i = 0; i < 4; ++i) {
      int4 sv = sp[qq * 4 + i];
      ay = SDOT4(woq[4 * i + 0], sv.x, ay);
      ay = SDOT4(woq[4 * i + 1], sv.y, ay);
      ay = SDOT4(woq[4 * i + 2], sv.z, ay);
      ay = SDOT4(woq[4 * i + 3], sv.w, ay);
    }
    ay += dpp_xor1(ay);
    if (h == 0) py[1][n] = ay;
    __syncthreads();
    if (t < 128) {
      int sum = py[1][t] + py[1][t + 128] + py[1][t + 256] + py[1][t + 384];
      yrow[(size_t)(TLEN - 1) * 128 + t] = fmaf((float)sum, so_r, bo_r);
    }
  }
}

// ---------------------------------------------------------------------------
extern "C" void kernel_launch(void* const* d_in, const int* in_sizes, int n_in,
                              void* d_out, int out_size, void* d_ws, size_t ws_size,
                              hipStream_t stream) {
  const int*   w     = (const int*)d_in[0];
  const float* emb   = (const float*)d_in[1];
  const float* W_in  = (const float*)d_in[2];
  const float* b_in  = (const float*)d_in[3];
  const float* W_out = (const float*)d_in[4];
  const float* b_out = (const float*)d_in[5];
  float* y = (float*)d_out;

  char* ws = (char*)d_ws;
  float* G   = (float*)ws;                      // 256 KB
  int*   WqI = (int*)(ws + (256 << 10));        // 256 KB
  int*   WoI = (int*)(ws + (512 << 10));        // 64 KB
  float* Sd  = (float*)(ws + (576 << 10));      // 2 KB
  float* So  = (float*)(ws + (580 << 10));      // 0.5 KB

  k_prep<<<896, 256, 0, stream>>>(emb, W_in, b_in, W_out, G, WqI, Sd, WoI, So);
  k_rec <<<BATCH, 1024, 0, stream>>>(w, G, WqI, Sd, WoI, So, b_out, y);
}

// Round 7
// 346.278 us; speedup vs baseline: 3.7958x; 3.7958x over previous
//
#include <hip/hip_runtime.h>
#include <stdint.h>
#include <math.h>

#define NALPH 128
#define NEMB  128
#define NST   512
#define BATCH 256
#define TLEN  256
#define FANIN 640   // NEMB + NST

#if __has_builtin(__builtin_amdgcn_sdot4)
#define SDOT4(a, b, c) __builtin_amdgcn_sdot4((a), (b), (c), false)
#else
__device__ __forceinline__ int SDOT4(int a, int b, int c) {
  c += (int)(signed char)(a)       * (int)(signed char)(b);
  c += (int)(signed char)(a >> 8)  * (int)(signed char)(b >> 8);
  c += (int)(signed char)(a >> 16) * (int)(signed char)(b >> 16);
  c += (int)(signed char)(a >> 24) * (int)(signed char)(b >> 24);
  return c;
}
#endif

// ---------------------------------------------------------------------------
// k_prep (896 blocks x 256 thr) — every branch previously passed:
//  [0,256)    G[tok*512+n] = b_in[n] + sum_e emb[tok,e]*W_in[n,e]  (fp32 exact)
//  [256,768)  W_s row-quant: WqT[kg*512+n] = pack4 i8, Sd[n] = mx/16129
//  [768,896)  W_out row-quant: WoQ[j*128+a] = pack4 i8, So[a] = mx/16129
// ---------------------------------------------------------------------------
__global__ __launch_bounds__(256) void k_prep(
    const float* __restrict__ emb, const float* __restrict__ W_in,
    const float* __restrict__ b_in, const float* __restrict__ W_out,
    float* __restrict__ G, int* __restrict__ WqT, float* __restrict__ Sd,
    int* __restrict__ WoQ, float* __restrict__ So)
{
  int bid = blockIdx.x, tid = threadIdx.x;
  if (bid < 256) {
    int idx = bid * 256 + tid;           // tok*512 + n
    int tok = idx >> 9, n = idx & 511;
    const float* er = emb + tok * NEMB;
    const float* wr = W_in + (size_t)n * FANIN;
    float acc = b_in[n];
#pragma unroll 8
    for (int e = 0; e < NEMB; ++e) acc += er[e] * wr[e];
    G[idx] = acc;
  } else if (bid < 768) {
    int n = bid - 256;                   // W_s row
    __shared__ float smax[128];
    float lw[4]; float m = 0.f;
    if (tid < 128) {
      const float* wr = W_in + (size_t)n * FANIN + NEMB + tid * 4;
#pragma unroll
      for (int i = 0; i < 4; ++i) { lw[i] = wr[i]; m = fmaxf(m, fabsf(lw[i])); }
      smax[tid] = m;
    }
    __syncthreads();
    for (int s2 = 64; s2 > 0; s2 >>= 1) {
      if (tid < s2) smax[tid] = fmaxf(smax[tid], smax[tid + s2]);
      __syncthreads();
    }
    float mx = smax[0];
    if (tid < 128) {
      float r = 127.f / mx;
      uint32_t pk = 0;
#pragma unroll
      for (int i = 0; i < 4; ++i) {
        int qv = (int)rintf(lw[i] * r);
        qv = qv < -127 ? -127 : (qv > 127 ? 127 : qv);
        pk |= (uint32_t)(qv & 0xff) << (8 * i);
      }
      WqT[tid * NST + n] = (int)pk;      // k_rec reads WqT[j*512+n] coalesced
    }
    if (tid == 0) Sd[n] = mx / 16129.0f;
  } else {
    int a = bid - 768;                   // W_out row
    __shared__ float smax[128];
    float lw[4]; float m = 0.f;
    if (tid < 128) {
      const float* wr = W_out + (size_t)a * NST + tid * 4;
#pragma unroll
      for (int i = 0; i < 4; ++i) { lw[i] = wr[i]; m = fmaxf(m, fabsf(lw[i])); }
      smax[tid] = m;
    }
    __syncthreads();
    for (int s2 = 64; s2 > 0; s2 >>= 1) {
      if (tid < s2) smax[tid] = fmaxf(smax[tid], smax[tid + s2]);
      __syncthreads();
    }
    float mx = smax[0];
    if (tid < 128) {
      float r = 127.f / mx;
      uint32_t pk = 0;
#pragma unroll
      for (int i = 0; i < 4; ++i) {
        int qv = (int)rintf(lw[i] * r);
        qv = qv < -127 ? -127 : (qv > 127 ? 127 : qv);
        pk |= (uint32_t)(qv & 0xff) << (8 * i);
      }
      WoQ[tid * 128 + a] = (int)pk;      // k_out reads WoQ[j*128+a] coalesced
    }
    if (tid == 0) So[a] = mx / 16129.0f;
  }
}

// ---------------------------------------------------------------------------
// k_rec (R2 structure, measured 257 us): 256 blocks x 512 threads, thread
// owns state col n = tid. W_s int8 register/AGPR-resident (128 dwords).
// Inner loop: 32 broadcast ds_read_b128 + 128 sdot4. One barrier/step.
// Change vs R2: stores i8 state (q8 already computed) instead of bf16.
// ---------------------------------------------------------------------------
__global__ __launch_bounds__(512, 2) void k_rec(
    const int* __restrict__ w, const float* __restrict__ G,
    const int* __restrict__ WqT, const float* __restrict__ Sd,
    signed char* __restrict__ qstates)
{
  __shared__ __align__(16) signed char qs[2][NST];
  int tid = threadIdx.x;
  int row = blockIdx.x;

  int wq[128];
#pragma unroll
  for (int j = 0; j < 128; ++j) wq[j] = WqT[j * NST + tid];  // coalesced
  float dn = Sd[tid];

  qs[0][tid] = 0;
  __syncthreads();

  const int* wr = w + row * TLEN;
  signed char* qrow = qstates + (size_t)row * TLEN * NST + tid;

  float g = G[wr[0] * NST + tid];
  int p = 0;
  for (int t = 0; t < TLEN; ++t) {
    int tok_n = (t < TLEN - 1) ? wr[t + 1] : 0;
    float g_n = G[tok_n * NST + tid];    // prefetch next step's fin
    const int4* sp = (const int4*)qs[p];
    int acc = 0;
#pragma unroll
    for (int j = 0; j < 32; ++j) {
      int4 sv = sp[j];                   // broadcast b128, conflict-free
      acc = SDOT4(wq[4 * j + 0], sv.x, acc);
      acc = SDOT4(wq[4 * j + 1], sv.y, acc);
      acc = SDOT4(wq[4 * j + 2], sv.z, acc);
      acc = SDOT4(wq[4 * j + 3], sv.w, acc);
    }
    float a = g + (float)acc * dn;
    a = fminf(fmaxf(a, -15.f), 15.f);
    float e = __expf(2.f * a);           // v_exp-based tanh
    float s = (e - 1.f) / (e + 1.f);
    signed char q8 = (signed char)(int)rintf(s * 127.f);
    qrow[(size_t)t * NST] = q8;
    qs[p ^ 1][tid] = q8;
    __syncthreads();
    g = g_n;
    p ^= 1;
  }
}

// ---------------------------------------------------------------------------
// k_out_i8: y[bt,a] = b_out[a] + So[a] * sum_k qs[bt,k]*qw[a,k]
// 2048 blocks x 256 thr. Block: 32 bt-rows x 128 a. States staged in LDS
// (16 KB, int dwords). Thread: a0 = tid&63 handles {a0, a0+64}, row-group
// gidx = tid>>6 (wave-uniform -> LDS reads are pure broadcasts).
// Per j: 2 coalesced WoQ dwords + 8 broadcast b32 + 16 sdot4.
// ---------------------------------------------------------------------------
__global__ __launch_bounds__(256) void k_out_i8(
    const signed char* __restrict__ qstates, const int* __restrict__ WoQ,
    const float* __restrict__ So, const float* __restrict__ b_out,
    float* __restrict__ y)
{
  __shared__ int sl[32 * 128];           // 16 KB
  int tid = threadIdx.x;
  size_t bt0 = (size_t)blockIdx.x * 32;
  const int4* gp = (const int4*)(qstates + bt0 * NST);
  int4* slp = (int4*)sl;
#pragma unroll
  for (int i = 0; i < 4; ++i) slp[tid + 256 * i] = gp[tid + 256 * i];
  __syncthreads();

  int a0 = tid & 63, gidx = tid >> 6;    // gidx uniform per wave
  const int* slg = sl + gidx * 8 * 128;
  int acc0[8], acc1[8];
#pragma unroll
  for (int r = 0; r < 8; ++r) { acc0[r] = 0; acc1[r] = 0; }

  for (int j = 0; j < 128; ++j) {
    int w0 = WoQ[j * 128 + a0];          // coalesced, L1/L2-hot (64 KB total)
    int w1 = WoQ[j * 128 + a0 + 64];
#pragma unroll
    for (int r = 0; r < 8; ++r) {
      int s = slg[r * 128 + j];          // broadcast across wave
      acc0[r] = SDOT4(w0, s, acc0[r]);
      acc1[r] = SDOT4(w1, s, acc1[r]);
    }
  }

  float s0 = So[a0], s1 = So[a0 + 64];
  float b0 = b_out[a0], b1 = b_out[a0 + 64];
#pragma unroll
  for (int r = 0; r < 8; ++r) {
    size_t rowb = (bt0 + gidx * 8 + r) * 128;
    y[rowb + a0]      = (float)acc0[r] * s0 + b0;
    y[rowb + a0 + 64] = (float)acc1[r] * s1 + b1;
  }
}

// ---------------------------------------------------------------------------
extern "C" void kernel_launch(void* const* d_in, const int* in_sizes, int n_in,
                              void* d_out, int out_size, void* d_ws, size_t ws_size,
                              hipStream_t stream) {
  const int*   w     = (const int*)d_in[0];
  const float* emb   = (const float*)d_in[1];
  const float* W_in  = (const float*)d_in[2];
  const float* b_in  = (const float*)d_in[3];
  const float* W_out = (const float*)d_in[4];
  const float* b_out = (const float*)d_in[5];
  float* y = (float*)d_out;

  char* ws = (char*)d_ws;
  float*       G       = (float*)ws;                      // 256 KB
  int*         WqT     = (int*)(ws + (256 << 10));        // 256 KB
  float*       Sd      = (float*)(ws + (512 << 10));      // 2 KB
  int*         WoQ     = (int*)(ws + (576 << 10));        // 64 KB
  float*       So      = (float*)(ws + (640 << 10));      // 0.5 KB
  signed char* qstates = (signed char*)(ws + (1024 << 10)); // 32 MB i8

  k_prep  <<<896, 256, 0, stream>>>(emb, W_in, b_in, W_out, G, WqT, Sd, WoQ, So);
  k_rec   <<<BATCH, 512, 0, stream>>>(w, G, WqT, Sd, qstates);
  k_out_i8<<<BATCH * TLEN / 32, 256, 0, stream>>>(qstates, WoQ, So, b_out, y);
}

// Round 8
// 338.653 us; speedup vs baseline: 3.8812x; 1.0225x over previous
//
#include <hip/hip_runtime.h>
#include <stdint.h>
#include <math.h>

#define NALPH 128
#define NEMB  128
#define NST   512
#define BATCH 256
#define TLEN  256
#define FANIN 640   // NEMB + NST

#if __has_builtin(__builtin_amdgcn_sdot4)
#define SDOT4(a, b, c) __builtin_amdgcn_sdot4((a), (b), (c), false)
#else
__device__ __forceinline__ int SDOT4(int a, int b, int c) {
  c += (int)(signed char)(a)       * (int)(signed char)(b);
  c += (int)(signed char)(a >> 8)  * (int)(signed char)(b >> 8);
  c += (int)(signed char)(a >> 16) * (int)(signed char)(b >> 16);
  c += (int)(signed char)(a >> 24) * (int)(signed char)(b >> 24);
  return c;
}
#endif

// ---------------------------------------------------------------------------
// k_prep (896 blocks x 256 thr) — verbatim R7 (passed):
//  [0,256)    G[tok*512+n] = b_in[n] + sum_e emb[tok,e]*W_in[n,e]  (fp32 exact)
//  [256,768)  W_s row-quant: WqT[kg*512+n] = pack4 i8, Sd[n] = mx/16129
//  [768,896)  W_out row-quant: WoQ[j*128+a] = pack4 i8, So[a] = mx/16129
// ---------------------------------------------------------------------------
__global__ __launch_bounds__(256) void k_prep(
    const float* __restrict__ emb, const float* __restrict__ W_in,
    const float* __restrict__ b_in, const float* __restrict__ W_out,
    float* __restrict__ G, int* __restrict__ WqT, float* __restrict__ Sd,
    int* __restrict__ WoQ, float* __restrict__ So)
{
  int bid = blockIdx.x, tid = threadIdx.x;
  if (bid < 256) {
    int idx = bid * 256 + tid;           // tok*512 + n
    int tok = idx >> 9, n = idx & 511;
    const float* er = emb + tok * NEMB;
    const float* wr = W_in + (size_t)n * FANIN;
    float acc = b_in[n];
#pragma unroll 8
    for (int e = 0; e < NEMB; ++e) acc += er[e] * wr[e];
    G[idx] = acc;
  } else if (bid < 768) {
    int n = bid - 256;                   // W_s row
    __shared__ float smax[128];
    float lw[4]; float m = 0.f;
    if (tid < 128) {
      const float* wr = W_in + (size_t)n * FANIN + NEMB + tid * 4;
#pragma unroll
      for (int i = 0; i < 4; ++i) { lw[i] = wr[i]; m = fmaxf(m, fabsf(lw[i])); }
      smax[tid] = m;
    }
    __syncthreads();
    for (int s2 = 64; s2 > 0; s2 >>= 1) {
      if (tid < s2) smax[tid] = fmaxf(smax[tid], smax[tid + s2]);
      __syncthreads();
    }
    float mx = smax[0];
    if (tid < 128) {
      float r = 127.f / mx;
      uint32_t pk = 0;
#pragma unroll
      for (int i = 0; i < 4; ++i) {
        int qv = (int)rintf(lw[i] * r);
        qv = qv < -127 ? -127 : (qv > 127 ? 127 : qv);
        pk |= (uint32_t)(qv & 0xff) << (8 * i);
      }
      WqT[tid * NST + n] = (int)pk;      // k_rec reads WqT[j*512+n] coalesced
    }
    if (tid == 0) Sd[n] = mx / 16129.0f;
  } else {
    int a = bid - 768;                   // W_out row
    __shared__ float smax[128];
    float lw[4]; float m = 0.f;
    if (tid < 128) {
      const float* wr = W_out + (size_t)a * NST + tid * 4;
#pragma unroll
      for (int i = 0; i < 4; ++i) { lw[i] = wr[i]; m = fmaxf(m, fabsf(lw[i])); }
      smax[tid] = m;
    }
    __syncthreads();
    for (int s2 = 64; s2 > 0; s2 >>= 1) {
      if (tid < s2) smax[tid] = fmaxf(smax[tid], smax[tid + s2]);
      __syncthreads();
    }
    float mx = smax[0];
    if (tid < 128) {
      float r = 127.f / mx;
      uint32_t pk = 0;
#pragma unroll
      for (int i = 0; i < 4; ++i) {
        int qv = (int)rintf(lw[i] * r);
        qv = qv < -127 ? -127 : (qv > 127 ? 127 : qv);
        pk |= (uint32_t)(qv & 0xff) << (8 * i);
      }
      WoQ[tid * 128 + a] = (int)pk;      // k_out reads WoQ[j*128+a] coalesced
    }
    if (tid == 0) So[a] = mx / 16129.0f;
  }
}

// ---------------------------------------------------------------------------
// k_rec: 256 blocks x 512 threads, thread owns state col n = tid. W_s int8
// register-resident (128 dwords). Inner loop: 32 broadcast ds_read_b128 +
// 128 sdot4 across FOUR independent accumulator chains (32-deep each; int
// adds are exact so result is bit-identical to the single-chain R7 version).
// One barrier/step. i8 state double-buffered in LDS; i8 states to global.
// ---------------------------------------------------------------------------
__global__ __launch_bounds__(512, 2) void k_rec(
    const int* __restrict__ w, const float* __restrict__ G,
    const int* __restrict__ WqT, const float* __restrict__ Sd,
    signed char* __restrict__ qstates)
{
  __shared__ __align__(16) signed char qs[2][NST];
  int tid = threadIdx.x;
  int row = blockIdx.x;

  int wq[128];
#pragma unroll
  for (int j = 0; j < 128; ++j) wq[j] = WqT[j * NST + tid];  // coalesced
  float dn = Sd[tid];

  qs[0][tid] = 0;
  __syncthreads();

  const int* wr = w + row * TLEN;
  signed char* qrow = qstates + (size_t)row * TLEN * NST + tid;

  float g = G[wr[0] * NST + tid];
  int p = 0;
  for (int t = 0; t < TLEN; ++t) {
    int tok_n = (t < TLEN - 1) ? wr[t + 1] : 0;
    float g_n = G[tok_n * NST + tid];    // prefetch next step's fin
    const int4* sp = (const int4*)qs[p];
    int a0 = 0, a1 = 0, a2 = 0, a3 = 0;  // 4 independent chains
#pragma unroll
    for (int j = 0; j < 8; ++j) {
      int4 s0 = sp[4 * j + 0];
      int4 s1 = sp[4 * j + 1];
      int4 s2 = sp[4 * j + 2];
      int4 s3 = sp[4 * j + 3];
      a0 = SDOT4(wq[16 * j +  0], s0.x, a0);
      a1 = SDOT4(wq[16 * j +  1], s0.y, a1);
      a2 = SDOT4(wq[16 * j +  2], s0.z, a2);
      a3 = SDOT4(wq[16 * j +  3], s0.w, a3);
      a0 = SDOT4(wq[16 * j +  4], s1.x, a0);
      a1 = SDOT4(wq[16 * j +  5], s1.y, a1);
      a2 = SDOT4(wq[16 * j +  6], s1.z, a2);
      a3 = SDOT4(wq[16 * j +  7], s1.w, a3);
      a0 = SDOT4(wq[16 * j +  8], s2.x, a0);
      a1 = SDOT4(wq[16 * j +  9], s2.y, a1);
      a2 = SDOT4(wq[16 * j + 10], s2.z, a2);
      a3 = SDOT4(wq[16 * j + 11], s2.w, a3);
      a0 = SDOT4(wq[16 * j + 12], s3.x, a0);
      a1 = SDOT4(wq[16 * j + 13], s3.y, a1);
      a2 = SDOT4(wq[16 * j + 14], s3.z, a2);
      a3 = SDOT4(wq[16 * j + 15], s3.w, a3);
    }
    int acc = (a0 + a1) + (a2 + a3);
    float a = g + (float)acc * dn;
    a = fminf(fmaxf(a, -15.f), 15.f);
    float e = __expf(2.f * a);           // tanh = 1 - 2/(e^(2a)+1)
    float s = fmaf(-2.f, __builtin_amdgcn_rcpf(e + 1.f), 1.f);
    signed char q8 = (signed char)(int)rintf(s * 127.f);
    qrow[(size_t)t * NST] = q8;
    qs[p ^ 1][tid] = q8;
    __syncthreads();
    g = g_n;
    p ^= 1;
  }
}

// ---------------------------------------------------------------------------
// k_out_i8: y[bt,a] = b_out[a] + So[a] * sum_k qs[bt,k]*qw[a,k]
// 2048 blocks x 256 thr. Block: 32 bt-rows x 128 a. States staged in LDS.
// vs R7: j blocked by 4 -> LDS reads are b128 (4x fewer LDS instructions).
// ---------------------------------------------------------------------------
__global__ __launch_bounds__(256) void k_out_i8(
    const signed char* __restrict__ qstates, const int* __restrict__ WoQ,
    const float* __restrict__ So, const float* __restrict__ b_out,
    float* __restrict__ y)
{
  __shared__ __align__(16) int sl[32 * 128];   // 16 KB
  int tid = threadIdx.x;
  size_t bt0 = (size_t)blockIdx.x * 32;
  const int4* gp = (const int4*)(qstates + bt0 * NST);
  int4* slp = (int4*)sl;
#pragma unroll
  for (int i = 0; i < 4; ++i) slp[tid + 256 * i] = gp[tid + 256 * i];
  __syncthreads();

  int a0 = tid & 63, gidx = tid >> 6;    // gidx uniform per wave
  const int* slg = sl + gidx * 8 * 128;
  int acc0[8], acc1[8];
#pragma unroll
  for (int r = 0; r < 8; ++r) { acc0[r] = 0; acc1[r] = 0; }

  for (int j4 = 0; j4 < 32; ++j4) {      // j = 4*j4 .. 4*j4+3
    int w00 = WoQ[(4 * j4 + 0) * 128 + a0];
    int w01 = WoQ[(4 * j4 + 0) * 128 + a0 + 64];
    int w10 = WoQ[(4 * j4 + 1) * 128 + a0];
    int w11 = WoQ[(4 * j4 + 1) * 128 + a0 + 64];
    int w20 = WoQ[(4 * j4 + 2) * 128 + a0];
    int w21 = WoQ[(4 * j4 + 2) * 128 + a0 + 64];
    int w30 = WoQ[(4 * j4 + 3) * 128 + a0];
    int w31 = WoQ[(4 * j4 + 3) * 128 + a0 + 64];
#pragma unroll
    for (int r = 0; r < 8; ++r) {
      int4 s = *(const int4*)&slg[r * 128 + 4 * j4];  // broadcast b128
      acc0[r] = SDOT4(w00, s.x, acc0[r]);
      acc1[r] = SDOT4(w01, s.x, acc1[r]);
      acc0[r] = SDOT4(w10, s.y, acc0[r]);
      acc1[r] = SDOT4(w11, s.y, acc1[r]);
      acc0[r] = SDOT4(w20, s.z, acc0[r]);
      acc1[r] = SDOT4(w21, s.z, acc1[r]);
      acc0[r] = SDOT4(w30, s.w, acc0[r]);
      acc1[r] = SDOT4(w31, s.w, acc1[r]);
    }
  }

  float s0 = So[a0], s1 = So[a0 + 64];
  float b0 = b_out[a0], b1 = b_out[a0 + 64];
#pragma unroll
  for (int r = 0; r < 8; ++r) {
    size_t rowb = (bt0 + gidx * 8 + r) * 128;
    y[rowb + a0]      = (float)acc0[r] * s0 + b0;
    y[rowb + a0 + 64] = (float)acc1[r] * s1 + b1;
  }
}

// ---------------------------------------------------------------------------
extern "C" void kernel_launch(void* const* d_in, const int* in_sizes, int n_in,
                              void* d_out, int out_size, void* d_ws, size_t ws_size,
                              hipStream_t stream) {
  const int*   w     = (const int*)d_in[0];
  const float* emb   = (const float*)d_in[1];
  const float* W_in  = (const float*)d_in[2];
  const float* b_in  = (const float*)d_in[3];
  const float* W_out = (const float*)d_in[4];
  const float* b_out = (const float*)d_in[5];
  float* y = (float*)d_out;

  char* ws = (char*)d_ws;
  float*       G       = (float*)ws;                        // 256 KB
  int*         WqT     = (int*)(ws + (256 << 10));          // 256 KB
  float*       Sd      = (float*)(ws + (512 << 10));        // 2 KB
  int*         WoQ     = (int*)(ws + (576 << 10));          // 64 KB
  float*       So      = (float*)(ws + (640 << 10));        // 0.5 KB
  signed char* qstates = (signed char*)(ws + (1024 << 10)); // 32 MB i8

  k_prep  <<<896, 256, 0, stream>>>(emb, W_in, b_in, W_out, G, WqT, Sd, WoQ, So);
  k_rec   <<<BATCH, 512, 0, stream>>>(w, G, WqT, Sd, qstates);
  k_out_i8<<<BATCH * TLEN / 32, 256, 0, stream>>>(qstates, WoQ, So, b_out, y);
}